// Round 7
// baseline (218.128 us; speedup 1.0000x reference)
//
#include <hip/hip_runtime.h>
#include <hip/hip_bf16.h>
#include <cmath>
#include <cstdint>

#define NB 8
#define HW 4096
#define PP 1024
#define C2 256

typedef _Float16 half_t;
typedef _Float16 half8 __attribute__((ext_vector_type(8)));
typedef _Float16 half4 __attribute__((ext_vector_type(4)));
typedef _Float16 half2t __attribute__((ext_vector_type(2)));
typedef float f32x4 __attribute__((ext_vector_type(4)));

// ---------------------------------------------------------------------------
// Merged prep kernel:
//  blocks [0,160):    cast weights fp32 -> fp16 into W16
//  blocks [160,4256): cast+transpose x [n][512 c][4096 p] fp32 ->
//                     x16t [n][4096 p][512 c] fp16.
// Transpose LDS layout is [64 c][68 p]: the 4 p-consecutive halfs a lane
// converts form ONE contiguous 8B store (conflict-free; old [p][c] layout was
// an 8-way write conflict), and the output phase does 8 scalar u16 reads
// whose banks spread over all 32 (2 lanes/bank = free).
// ---------------------------------------------------------------------------
__global__ __launch_bounds__(256) void prep_k(
    const float* __restrict__ tw, const float* __restrict__ pw,
    const float* __restrict__ gw, const float* __restrict__ ow,
    half_t* __restrict__ W16,
    const float* __restrict__ x, half_t* __restrict__ x16t)
{
    const int tid = threadIdx.x;
    const int bx = blockIdx.x;

    if (bx < 160) {
        int gid = bx * 256 + tid;
        size_t i0 = (size_t)gid * 8;
        const float* src; size_t off;
        if (i0 < 32768)       { src = tw; off = i0; }
        else if (i0 < 65536)  { src = pw; off = i0 - 32768; }
        else if (i0 < 196608) { src = gw; off = i0 - 65536; }
        else                  { src = ow; off = i0 - 196608; }
        float4 a = *(const float4*)&src[off];
        float4 b = *(const float4*)&src[off + 4];
        half8 h;
        h[0] = (half_t)a.x; h[1] = (half_t)a.y; h[2] = (half_t)a.z; h[3] = (half_t)a.w;
        h[4] = (half_t)b.x; h[5] = (half_t)b.y; h[6] = (half_t)b.z; h[7] = (half_t)b.w;
        *(half8*)&W16[i0] = h;
        return;
    }

    __shared__ half_t U[64][68];          // [c][p], 8704 B
    const int b = bx - 160;
    const int n  = b >> 9;
    const int bxx = b & 511;
    const int c0 = (bxx & 7) * 64;
    const int p0 = (bxx >> 3) * 64;

#pragma unroll
    for (int it = 0; it < 4; ++it) {
        int c = (tid >> 4) + 16 * it;
        int p4 = (tid & 15) * 4;
        float4 v = *(const float4*)&x[((size_t)n * 512 + c0 + c) * HW + p0 + p4];
        half4 h;
        h[0] = (half_t)v.x; h[1] = (half_t)v.y;
        h[2] = (half_t)v.z; h[3] = (half_t)v.w;
        *(half4*)&U[c][p4] = h;
    }
    __syncthreads();
#pragma unroll
    for (int it = 0; it < 2; ++it) {
        int p = (tid >> 3) + 32 * it;
        int ch = (tid & 7) * 8;
        half8 o;
#pragma unroll
        for (int j = 0; j < 8; ++j) o[j] = U[ch + j][p];
        *(half8*)&x16t[((size_t)n * HW + p0 + p) * 512 + c0 + ch] = o;
    }
}

// ---------------------------------------------------------------------------
// Fused projection GEMM, 128x128 tile, BK=64, 4 waves.
// y==0: A=[theta|phi]; theta transposed out, phi pooled+transposed.
// y==1,2: A=g rows; pooled 2x2 -> g16.
// Staging: global_load_lds dwordx4; LINEAR LDS [128][64] + XOR swizzle
// (chunk ^= row&7) applied on BOTH global source and ds_read (rule #21).
// launch_bounds(256,3): grid is 768 = 3 x 256 CUs; at 2 blocks/CU the grid
// ran 1.5 generations (33% tail). 3 blocks/CU -> all 768 resident, one
// generation. LDS 36.9KB x 3 = 110KB < 160; VGPR cap 170 >> need, no spill.
// ---------------------------------------------------------------------------
#define SWZ(row, chunk) (((row) << 6) + ((((chunk) ^ ((row) & 7))) << 3))

__global__ __launch_bounds__(256, 3) void proj_k(
    const half_t* __restrict__ W16, const float* __restrict__ theta_b,
    const float* __restrict__ phi_b, const float* __restrict__ g_b,
    const half_t* __restrict__ x16t, half_t* __restrict__ theta16,
    half_t* __restrict__ phi16, half_t* __restrict__ g16)
{
    __shared__ __align__(16) char smem[36864];
    half_t* As = (half_t*)smem;              // [128][64] linear, swizzled
    half_t* Bs = (half_t*)(smem + 16384);    // [128][64] linear, swizzled

    const int tid = threadIdx.x;
    const int wave = tid >> 6, lane = tid & 63;
    const int quad = lane >> 4, lq = lane & 15;
    const int wn = (wave & 1) * 64, wm = (wave >> 1) * 64;
    const int n = blockIdx.z;
    const int p0 = blockIdx.x * 128;
    const int ysel = blockIdx.y;

    const half_t* A16 = (ysel == 0) ? W16
                        : (W16 + 65536 + (size_t)(ysel - 1) * 128 * 512);

    // staging lane decomposition: 8 lanes/row, 16B chunk each
    const int sr  = lane >> 3;          // row-within-8-group
    const int scl = lane & 7;           // LDS chunk this lane's slot holds
    const int scg = scl ^ sr;           // global chunk to fetch (involution)

    f32x4 acc[4][4];
#pragma unroll
    for (int mt = 0; mt < 4; ++mt)
#pragma unroll
        for (int nt = 0; nt < 4; ++nt)
            acc[mt][nt] = (f32x4){0.f, 0.f, 0.f, 0.f};

    for (int c0 = 0; c0 < 512; c0 += 64) {
        // async global -> LDS staging: each wave fills rows [wave*32, +32)
        // of both tiles; 4 calls of 1KB per tile per wave.
#pragma unroll
        for (int i = 0; i < 4; ++i) {
            int rb = (wave << 5) + (i << 3);        // wave-uniform row base
            int r = rb + sr;
            __builtin_amdgcn_global_load_lds(
                (const __attribute__((address_space(1))) uint32_t*)
                    &A16[(size_t)r * 512 + c0 + scg * 8],
                (__attribute__((address_space(3))) uint32_t*)&As[rb * 64],
                16, 0, 0);
        }
#pragma unroll
        for (int i = 0; i < 4; ++i) {
            int rb = (wave << 5) + (i << 3);
            int r = rb + sr;
            __builtin_amdgcn_global_load_lds(
                (const __attribute__((address_space(1))) uint32_t*)
                    &x16t[((size_t)n * HW + p0 + r) * 512 + c0 + scg * 8],
                (__attribute__((address_space(3))) uint32_t*)&Bs[rb * 64],
                16, 0, 0);
        }
        __syncthreads();
#pragma unroll
        for (int ks = 0; ks < 2; ++ks) {
            half8 af[4], bf[4];
#pragma unroll
            for (int mt = 0; mt < 4; ++mt)
                af[mt] = *(const half8*)&As[SWZ(wm + mt * 16 + lq, ks * 4 + quad)];
#pragma unroll
            for (int nt = 0; nt < 4; ++nt)
                bf[nt] = *(const half8*)&Bs[SWZ(wn + nt * 16 + lq, ks * 4 + quad)];
#pragma unroll
            for (int mt = 0; mt < 4; ++mt)
#pragma unroll
                for (int nt = 0; nt < 4; ++nt)
                    acc[mt][nt] = __builtin_amdgcn_mfma_f32_16x16x32_f16(
                        af[mt], bf[nt], acc[mt][nt], 0, 0, 0);
        }
        __syncthreads();
    }

    if (ysel == 0) {
        half_t* Cs = (half_t*)smem;   // [64][136] phi C-tile
        if (wm == 0) {
#pragma unroll
            for (int mt = 0; mt < 4; ++mt) {
                float4 bv = *(const float4*)&theta_b[mt * 16 + quad * 4];
#pragma unroll
                for (int nt = 0; nt < 4; ++nt) {
                    int q = p0 + wn + nt * 16 + lq;
                    half4 h;
                    h[0] = (half_t)(acc[mt][nt][0] + bv.x);
                    h[1] = (half_t)(acc[mt][nt][1] + bv.y);
                    h[2] = (half_t)(acc[mt][nt][2] + bv.z);
                    h[3] = (half_t)(acc[mt][nt][3] + bv.w);
                    *(half4*)&theta16[((size_t)n * HW + q) * 64 + mt * 16 + quad * 4] = h;
                }
            }
        } else {
#pragma unroll
            for (int mt = 0; mt < 4; ++mt) {
                float4 bv = *(const float4*)&phi_b[mt * 16 + quad * 4];
#pragma unroll
                for (int nt = 0; nt < 4; ++nt) {
                    int col = wn + nt * 16 + lq;
                    int mr = mt * 16 + quad * 4;
                    Cs[(mr + 0) * 136 + col] = (half_t)(acc[mt][nt][0] + bv.x);
                    Cs[(mr + 1) * 136 + col] = (half_t)(acc[mt][nt][1] + bv.y);
                    Cs[(mr + 2) * 136 + col] = (half_t)(acc[mt][nt][2] + bv.z);
                    Cs[(mr + 3) * 136 + col] = (half_t)(acc[mt][nt][3] + bv.w);
                }
            }
        }
        __syncthreads();
        {
            int pw = tid >> 3;
            int kc = (tid & 7) * 8;
            half8 o;
#pragma unroll
            for (int jj = 0; jj < 8; ++jj) {
                int k = kc + jj;
                float v0 = (float)Cs[k * 136 + 2 * pw];
                float v1 = (float)Cs[k * 136 + 2 * pw + 1];
                float v2 = (float)Cs[k * 136 + 64 + 2 * pw];
                float v3 = (float)Cs[k * 136 + 65 + 2 * pw];
                o[jj] = (half_t)fmaxf(fmaxf(v0, v1), fmaxf(v2, v3));
            }
            *(half8*)&phi16[((size_t)n * PP + (p0 >> 7) * 32 + pw) * 64 + kc] = o;
        }
    } else {
        const int m0 = (ysel - 1) * 128;
        half_t* Cs = (half_t*)smem;   // [128][136]
#pragma unroll
        for (int mt = 0; mt < 4; ++mt) {
            float4 bv = *(const float4*)&g_b[m0 + wm + mt * 16 + quad * 4];
#pragma unroll
            for (int nt = 0; nt < 4; ++nt) {
                int col = wn + nt * 16 + lq;
                int mr = wm + mt * 16 + quad * 4;
                Cs[(mr + 0) * 136 + col] = (half_t)(acc[mt][nt][0] + bv.x);
                Cs[(mr + 1) * 136 + col] = (half_t)(acc[mt][nt][1] + bv.y);
                Cs[(mr + 2) * 136 + col] = (half_t)(acc[mt][nt][2] + bv.z);
                Cs[(mr + 3) * 136 + col] = (half_t)(acc[mt][nt][3] + bv.w);
            }
        }
        __syncthreads();
#pragma unroll
        for (int i = 0; i < 16; ++i) {
            int m = (tid >> 5) + 8 * i;
            int pw = tid & 31;
            float v0 = (float)Cs[m * 136 + 2 * pw];
            float v1 = (float)Cs[m * 136 + 2 * pw + 1];
            float v2 = (float)Cs[m * 136 + 64 + 2 * pw];
            float v3 = (float)Cs[m * 136 + 65 + 2 * pw];
            g16[((size_t)n * C2 + m0 + m) * PP + (p0 >> 7) * 32 + pw] =
                (half_t)fmaxf(fmaxf(v0, v1), fmaxf(v2, v3));
        }
    }
}

// ---------------------------------------------------------------------------
// Fused flash-attention + output conv. Block = (n, 64 q), 4 waves.
// EXACT round-0 version (proven 80 us; VGPR 124 <= 128 cliff, LDS 36.9 KB,
// 2 blocks/CU). Rounds 1-5 established: any restructure that pushes VGPR
// past 128 or LDS past ~39 KB loses a resident block and regresses.
// ---------------------------------------------------------------------------
__global__ __launch_bounds__(256, 2) void attn_fused_k(
    const half_t* __restrict__ theta16,   // [n][4096][64]
    const half_t* __restrict__ phi16,     // [n][1024][64]
    const half_t* __restrict__ g16,       // [n][256][1024]
    const half_t* __restrict__ W16o,      // [512][256] fp16
    const float* __restrict__ out_b,      // [512]
    const float* __restrict__ x,          // [n][512][4096] fp32
    const float* __restrict__ gam,
    float* __restrict__ outF)             // [n][512][4096] fp32
{
    __shared__ half_t P[64][264];          // 33792 B (scores, then O^T)
    __shared__ float redM[4][64];
    __shared__ float redS[4][64];
    __shared__ float Ms[64], alpha_s[64], l_s[64], inv_s[64];

    const int tid  = threadIdx.x;
    const int wave = tid >> 6;
    const int lane = tid & 63;
    const int quad = lane >> 4;
    const int lq   = lane & 15;
    const int n  = blockIdx.y;
    const int q0 = blockIdx.x * 64;
    const int cb = wave * 64;

    const half_t* thN  = theta16 + ((size_t)n * HW + q0) * 64;
    const half_t* phiN = phi16 + (size_t)n * PP * 64;
    const half_t* gN   = g16 + (size_t)n * C2 * PP;

    if (tid < 64) { Ms[tid] = -1e30f; l_s[tid] = 0.f; }

    f32x4 acc[4][4];   // [ct][qt] : rows c, cols q
#pragma unroll
    for (int ct = 0; ct < 4; ++ct)
#pragma unroll
        for (int qt = 0; qt < 4; ++qt)
            acc[ct][qt] = (f32x4){0.f, 0.f, 0.f, 0.f};

    for (int chunk = 0; chunk < 4; ++chunk) {
        const int pch = chunk * 256;

        // --- E phase: wave covers 64 p of chunk ---
        half8 tb[4][2];
#pragma unroll
        for (int qt = 0; qt < 4; ++qt)
#pragma unroll
            for (int kb = 0; kb < 2; ++kb)
                tb[qt][kb] = *(const half8*)&thN[(size_t)(qt * 16 + lq) * 64 + kb * 32 + quad * 8];

        float mreg[4] = {-1e30f, -1e30f, -1e30f, -1e30f};
#pragma unroll
        for (int pt = 0; pt < 4; ++pt) {
            int pl = wave * 64 + pt * 16;
            const half_t* pr = &phiN[(size_t)(pch + pl + lq) * 64];
            half8 a0 = *(const half8*)&pr[quad * 8];
            half8 a1 = *(const half8*)&pr[32 + quad * 8];
#pragma unroll
            for (int qt = 0; qt < 4; ++qt) {
                f32x4 c = {0.f, 0.f, 0.f, 0.f};
                c = __builtin_amdgcn_mfma_f32_16x16x32_f16(a0, tb[qt][0], c, 0, 0, 0);
                c = __builtin_amdgcn_mfma_f32_16x16x32_f16(a1, tb[qt][1], c, 0, 0, 0);
                mreg[qt] = fmaxf(mreg[qt], fmaxf(fmaxf(c[0], c[1]), fmaxf(c[2], c[3])));
                half2t h0; h0[0] = (half_t)c[0]; h0[1] = (half_t)c[1];
                half2t h1; h1[0] = (half_t)c[2]; h1[1] = (half_t)c[3];
                *(half2t*)&P[qt * 16 + lq][pl + quad * 4]     = h0;
                *(half2t*)&P[qt * 16 + lq][pl + quad * 4 + 2] = h1;
            }
        }
#pragma unroll
        for (int qt = 0; qt < 4; ++qt) {
            float m = mreg[qt];
            m = fmaxf(m, __shfl_xor(m, 16));
            m = fmaxf(m, __shfl_xor(m, 32));
            mreg[qt] = m;
        }
        if (quad == 0) {
#pragma unroll
            for (int qt = 0; qt < 4; ++qt) redM[wave][qt * 16 + lq] = mreg[qt];
        }
        __syncthreads();                                   // B1

        if (tid < 64) {
            float cm = fmaxf(fmaxf(redM[0][tid], redM[1][tid]),
                             fmaxf(redM[2][tid], redM[3][tid]));
            float Mo = Ms[tid];
            float Mn = fmaxf(Mo, cm);
            alpha_s[tid] = __expf(Mo - Mn);
            Ms[tid] = Mn;
        }
        __syncthreads();                                   // B2

        // rescale O accumulators
        {
            float al[4];
#pragma unroll
            for (int qt = 0; qt < 4; ++qt) al[qt] = alpha_s[qt * 16 + lq];
#pragma unroll
            for (int ct = 0; ct < 4; ++ct)
#pragma unroll
                for (int qt = 0; qt < 4; ++qt)
#pragma unroll
                    for (int r = 0; r < 4; ++r) acc[ct][qt][r] *= al[qt];
        }

        // exp pass: thread = (q = tid&63, seg = wave)
        {
            int q = tid & 63, seg = tid >> 6;
            float M = Ms[q];
            float s = 0.f;
#pragma unroll
            for (int j = 0; j < 8; ++j) {
                half8 v = *(const half8*)&P[q][seg * 64 + j * 8];
                half8 o;
#pragma unroll
                for (int e = 0; e < 8; ++e) {
                    float f = __expf((float)v[e] - M);
                    s += f;
                    o[e] = (half_t)f;
                }
                *(half8*)&P[q][seg * 64 + j * 8] = o;
            }
            redS[seg][q] = s;
        }
        __syncthreads();                                   // B3

        if (tid < 64)
            l_s[tid] = l_s[tid] * alpha_s[tid]
                     + redS[0][tid] + redS[1][tid] + redS[2][tid] + redS[3][tid];

        // --- PV: wave covers c in [cb, cb+64); k over this chunk ---
#pragma unroll
        for (int kb = 0; kb < 8; ++kb) {
            half8 b[4];
#pragma unroll
            for (int qt = 0; qt < 4; ++qt)
                b[qt] = *(const half8*)&P[qt * 16 + lq][kb * 32 + quad * 8];
#pragma unroll
            for (int ct = 0; ct < 4; ++ct) {
                half8 a = *(const half8*)&gN[(size_t)(cb + ct * 16 + lq) * PP + pch + kb * 32 + quad * 8];
#pragma unroll
                for (int qt = 0; qt < 4; ++qt)
                    acc[ct][qt] = __builtin_amdgcn_mfma_f32_16x16x32_f16(a, b[qt], acc[ct][qt], 0, 0, 0);
            }
        }
        __syncthreads();                                   // B4
    }

    if (tid < 64) inv_s[tid] = 1.0f / l_s[tid];
    __syncthreads();

    // stage O^T fp16 into P as [q][c]
    {
        float iv[4];
#pragma unroll
        for (int qt = 0; qt < 4; ++qt) iv[qt] = inv_s[qt * 16 + lq];
#pragma unroll
        for (int ct = 0; ct < 4; ++ct) {
#pragma unroll
            for (int qt = 0; qt < 4; ++qt) {
                half2t h0, h1;
                h0[0] = (half_t)(acc[ct][qt][0] * iv[qt]);
                h0[1] = (half_t)(acc[ct][qt][1] * iv[qt]);
                h1[0] = (half_t)(acc[ct][qt][2] * iv[qt]);
                h1[1] = (half_t)(acc[ct][qt][3] * iv[qt]);
                *(half2t*)&P[qt * 16 + lq][cb + ct * 16 + quad * 4]     = h0;
                *(half2t*)&P[qt * 16 + lq][cb + ct * 16 + quad * 4 + 2] = h1;
            }
        }
    }
    __syncthreads();

    // out-GEMM: [512 m][64 q] over k=256, 2 m-passes
    const float g0 = gam[0];
#pragma unroll
    for (int pass = 0; pass < 2; ++pass) {
        const int mb = pass * 256 + wave * 64;
        f32x4 acc2[4][4];
#pragma unroll
        for (int mt = 0; mt < 4; ++mt)
#pragma unroll
            for (int qt = 0; qt < 4; ++qt)
                acc2[mt][qt] = (f32x4){0.f, 0.f, 0.f, 0.f};

#pragma unroll
        for (int kb = 0; kb < 8; ++kb) {
            half8 b[4];
#pragma unroll
            for (int qt = 0; qt < 4; ++qt)
                b[qt] = *(const half8*)&P[qt * 16 + lq][kb * 32 + quad * 8];
#pragma unroll
            for (int mt = 0; mt < 4; ++mt) {
                half8 a = *(const half8*)&W16o[(size_t)(mb + mt * 16 + lq) * 256 + kb * 32 + quad * 8];
#pragma unroll
                for (int qt = 0; qt < 4; ++qt)
                    acc2[mt][qt] = __builtin_amdgcn_mfma_f32_16x16x32_f16(a, b[qt], acc2[mt][qt], 0, 0, 0);
            }
        }

#pragma unroll
        for (int mt = 0; mt < 4; ++mt) {
            float4 bv = *(const float4*)&out_b[mb + mt * 16 + quad * 4];
#pragma unroll
            for (int qt = 0; qt < 4; ++qt) {
                int qg = q0 + qt * 16 + lq;
                int m = mb + mt * 16 + quad * 4;
                size_t off = ((size_t)(n * 512 + m)) * HW + qg;
                outF[off]          = g0 * (acc2[mt][qt][0] + bv.x) + x[off];
                outF[off + HW]     = g0 * (acc2[mt][qt][1] + bv.y) + x[off + HW];
                outF[off + 2*HW]   = g0 * (acc2[mt][qt][2] + bv.z) + x[off + 2*HW];
                outF[off + 3*HW]   = g0 * (acc2[mt][qt][3] + bv.w) + x[off + 3*HW];
            }
        }
    }
}

// ---------------------------------------------------------------------------
extern "C" void kernel_launch(void* const* d_in, const int* in_sizes, int n_in,
                              void* d_out, int out_size, void* d_ws, size_t ws_size,
                              hipStream_t stream)
{
    const float* x       = (const float*)d_in[0];
    const float* theta_w = (const float*)d_in[1];
    const float* theta_b = (const float*)d_in[2];
    const float* phi_w   = (const float*)d_in[3];
    const float* phi_b   = (const float*)d_in[4];
    const float* g_w     = (const float*)d_in[5];
    const float* g_b     = (const float*)d_in[6];
    const float* out_w   = (const float*)d_in[7];
    const float* out_b   = (const float*)d_in[8];
    const float* gamma   = (const float*)d_in[9];
    float* out = (float*)d_out;

    char* wsb = (char*)d_ws;
    half_t* x16t    = (half_t*)wsb;                    // 33,554,432 B
    half_t* W16     = (half_t*)(wsb + 33554432);       // 655,360 B
    half_t* theta16 = (half_t*)(wsb + 34209792);       // 4,194,304 B
    half_t* phi16   = (half_t*)(wsb + 38404096);       // 1,048,576 B
    half_t* g16     = (half_t*)(wsb + 39452672);       // 4,194,304 B

    // 1) weights -> fp16  AND  x -> x16t (merged, one launch)
    prep_k<<<160 + 512 * NB, 256, 0, stream>>>(
        theta_w, phi_w, g_w, out_w, W16, x, x16t);
    // 2) all projections in one launch (768 blocks = 3/CU, one generation)
    proj_k<<<dim3(32, 3, NB), 256, 0, stream>>>(
        W16, theta_b, phi_b, g_b, x16t, theta16, phi16, g16);
    // 3) fused flash attention + output conv + gamma + residual -> out
    attn_fused_k<<<dim3(HW / 64, NB), 256, 0, stream>>>(
        theta16, phi16, g16, W16 + 196608, out_b, x, gamma, out);
}

// Round 8
// 212.755 us; speedup vs baseline: 1.0253x; 1.0253x over previous
//
#include <hip/hip_runtime.h>
#include <hip/hip_bf16.h>
#include <cmath>
#include <cstdint>

#define NB 8
#define HW 4096
#define PP 1024
#define C2 256

typedef _Float16 half_t;
typedef _Float16 half8 __attribute__((ext_vector_type(8)));
typedef _Float16 half4 __attribute__((ext_vector_type(4)));
typedef _Float16 half2t __attribute__((ext_vector_type(2)));
typedef float f32x4 __attribute__((ext_vector_type(4)));

// ---------------------------------------------------------------------------
// Cast all weights fp32 -> fp16 into W16: [theta 64x512 | phi 64x512 |
// g 256x512 | out 512x256]   (r6 version, proven)
// ---------------------------------------------------------------------------
__global__ __launch_bounds__(256) void cast_w_k(
    const float* __restrict__ tw, const float* __restrict__ pw,
    const float* __restrict__ gw, const float* __restrict__ ow,
    half_t* __restrict__ W16)
{
    int gid = blockIdx.x * 256 + threadIdx.x;
    size_t i0 = (size_t)gid * 8;
    const float* src; size_t off;
    if (i0 < 32768)       { src = tw; off = i0; }
    else if (i0 < 65536)  { src = pw; off = i0 - 32768; }
    else if (i0 < 196608) { src = gw; off = i0 - 65536; }
    else                  { src = ow; off = i0 - 196608; }
    float4 a = *(const float4*)&src[off];
    float4 b = *(const float4*)&src[off + 4];
    half8 h;
    h[0] = (half_t)a.x; h[1] = (half_t)a.y; h[2] = (half_t)a.z; h[3] = (half_t)a.w;
    h[4] = (half_t)b.x; h[5] = (half_t)b.y; h[6] = (half_t)b.z; h[7] = (half_t)b.w;
    *(half8*)&W16[i0] = h;
}

// ---------------------------------------------------------------------------
// Cast+transpose x: [n][512 c][4096 p] fp32 -> x16t [n][4096 p][512 c] fp16
// (r6 version, proven)
// ---------------------------------------------------------------------------
__global__ __launch_bounds__(256) void cast_xt_k(const float* __restrict__ x,
                                                 half_t* __restrict__ x16t)
{
    __shared__ half_t T[64][72];
    const int tid = threadIdx.x;
    const int n = blockIdx.y;
    const int c0 = (blockIdx.x & 7) * 64;
    const int p0 = (blockIdx.x >> 3) * 64;

#pragma unroll
    for (int it = 0; it < 4; ++it) {
        int c = (tid >> 4) + 16 * it;
        int p4 = (tid & 15) * 4;
        float4 v = *(const float4*)&x[((size_t)n * 512 + c0 + c) * HW + p0 + p4];
        T[p4 + 0][c] = (half_t)v.x;
        T[p4 + 1][c] = (half_t)v.y;
        T[p4 + 2][c] = (half_t)v.z;
        T[p4 + 3][c] = (half_t)v.w;
    }
    __syncthreads();
#pragma unroll
    for (int it = 0; it < 2; ++it) {
        int p = (tid >> 3) + 32 * it;
        int ch = (tid & 7) * 8;
        half8 o = *(const half8*)&T[p][ch];
        *(half8*)&x16t[((size_t)n * HW + p0 + p) * 512 + c0 + ch] = o;
    }
}

// ---------------------------------------------------------------------------
// Fused projection GEMM, 128x128 tile, BK=64, 4 waves (r6 staging, proven).
// XCD swizzle: 1D grid, n = bid & 7. With round-robin dispatch, XCD k gets
// only n==k blocks, so each XCD's x16t reuse set is 4 MB (= its L2): the
// ysel=1,2 passes re-read x16t from L2 instead of HBM.
// ---------------------------------------------------------------------------
#define SWZ(row, chunk) (((row) << 6) + ((((chunk) ^ ((row) & 7))) << 3))

__global__ __launch_bounds__(256, 2) void proj_k(
    const half_t* __restrict__ W16, const float* __restrict__ theta_b,
    const float* __restrict__ phi_b, const float* __restrict__ g_b,
    const half_t* __restrict__ x16t, half_t* __restrict__ theta16,
    half_t* __restrict__ phi16, half_t* __restrict__ g16)
{
    __shared__ __align__(16) char smem[36864];
    half_t* As = (half_t*)smem;              // [128][64] linear, swizzled
    half_t* Bs = (half_t*)(smem + 16384);    // [128][64] linear, swizzled

    const int tid = threadIdx.x;
    const int wave = tid >> 6, lane = tid & 63;
    const int quad = lane >> 4, lq = lane & 15;
    const int wn = (wave & 1) * 64, wm = (wave >> 1) * 64;

    // XCD-aware decomposition: n = bid&7 -> all blocks of one n on one XCD
    const int bid  = blockIdx.x;
    const int n    = bid & 7;
    const int rest = bid >> 3;            // 0..95
    const int p0   = (rest & 31) * 128;
    const int ysel = rest >> 5;           // 0..2

    const half_t* A16 = (ysel == 0) ? W16
                        : (W16 + 65536 + (size_t)(ysel - 1) * 128 * 512);

    // staging lane decomposition: 8 lanes/row, 16B chunk each
    const int sr  = lane >> 3;          // row-within-8-group
    const int scl = lane & 7;           // LDS chunk this lane's slot holds
    const int scg = scl ^ sr;           // global chunk to fetch (involution)

    f32x4 acc[4][4];
#pragma unroll
    for (int mt = 0; mt < 4; ++mt)
#pragma unroll
        for (int nt = 0; nt < 4; ++nt)
            acc[mt][nt] = (f32x4){0.f, 0.f, 0.f, 0.f};

    for (int c0 = 0; c0 < 512; c0 += 64) {
#pragma unroll
        for (int i = 0; i < 4; ++i) {
            int rb = (wave << 5) + (i << 3);        // wave-uniform row base
            int r = rb + sr;
            __builtin_amdgcn_global_load_lds(
                (const __attribute__((address_space(1))) uint32_t*)
                    &A16[(size_t)r * 512 + c0 + scg * 8],
                (__attribute__((address_space(3))) uint32_t*)&As[rb * 64],
                16, 0, 0);
        }
#pragma unroll
        for (int i = 0; i < 4; ++i) {
            int rb = (wave << 5) + (i << 3);
            int r = rb + sr;
            __builtin_amdgcn_global_load_lds(
                (const __attribute__((address_space(1))) uint32_t*)
                    &x16t[((size_t)n * HW + p0 + r) * 512 + c0 + scg * 8],
                (__attribute__((address_space(3))) uint32_t*)&Bs[rb * 64],
                16, 0, 0);
        }
        __syncthreads();
#pragma unroll
        for (int ks = 0; ks < 2; ++ks) {
            half8 af[4], bf[4];
#pragma unroll
            for (int mt = 0; mt < 4; ++mt)
                af[mt] = *(const half8*)&As[SWZ(wm + mt * 16 + lq, ks * 4 + quad)];
#pragma unroll
            for (int nt = 0; nt < 4; ++nt)
                bf[nt] = *(const half8*)&Bs[SWZ(wn + nt * 16 + lq, ks * 4 + quad)];
#pragma unroll
            for (int mt = 0; mt < 4; ++mt)
#pragma unroll
                for (int nt = 0; nt < 4; ++nt)
                    acc[mt][nt] = __builtin_amdgcn_mfma_f32_16x16x32_f16(
                        af[mt], bf[nt], acc[mt][nt], 0, 0, 0);
        }
        __syncthreads();
    }

    if (ysel == 0) {
        half_t* Cs = (half_t*)smem;   // [64][136] phi C-tile
        if (wm == 0) {
#pragma unroll
            for (int mt = 0; mt < 4; ++mt) {
                float4 bv = *(const float4*)&theta_b[mt * 16 + quad * 4];
#pragma unroll
                for (int nt = 0; nt < 4; ++nt) {
                    int q = p0 + wn + nt * 16 + lq;
                    half4 h;
                    h[0] = (half_t)(acc[mt][nt][0] + bv.x);
                    h[1] = (half_t)(acc[mt][nt][1] + bv.y);
                    h[2] = (half_t)(acc[mt][nt][2] + bv.z);
                    h[3] = (half_t)(acc[mt][nt][3] + bv.w);
                    *(half4*)&theta16[((size_t)n * HW + q) * 64 + mt * 16 + quad * 4] = h;
                }
            }
        } else {
#pragma unroll
            for (int mt = 0; mt < 4; ++mt) {
                float4 bv = *(const float4*)&phi_b[mt * 16 + quad * 4];
#pragma unroll
                for (int nt = 0; nt < 4; ++nt) {
                    int col = wn + nt * 16 + lq;
                    int mr = mt * 16 + quad * 4;
                    Cs[(mr + 0) * 136 + col] = (half_t)(acc[mt][nt][0] + bv.x);
                    Cs[(mr + 1) * 136 + col] = (half_t)(acc[mt][nt][1] + bv.y);
                    Cs[(mr + 2) * 136 + col] = (half_t)(acc[mt][nt][2] + bv.z);
                    Cs[(mr + 3) * 136 + col] = (half_t)(acc[mt][nt][3] + bv.w);
                }
            }
        }
        __syncthreads();
        {
            int pw = tid >> 3;
            int kc = (tid & 7) * 8;
            half8 o;
#pragma unroll
            for (int jj = 0; jj < 8; ++jj) {
                int k = kc + jj;
                float v0 = (float)Cs[k * 136 + 2 * pw];
                float v1 = (float)Cs[k * 136 + 2 * pw + 1];
                float v2 = (float)Cs[k * 136 + 64 + 2 * pw];
                float v3 = (float)Cs[k * 136 + 65 + 2 * pw];
                o[jj] = (half_t)fmaxf(fmaxf(v0, v1), fmaxf(v2, v3));
            }
            *(half8*)&phi16[((size_t)n * PP + (p0 >> 7) * 32 + pw) * 64 + kc] = o;
        }
    } else {
        const int m0 = (ysel - 1) * 128;
        half_t* Cs = (half_t*)smem;   // [128][136]
#pragma unroll
        for (int mt = 0; mt < 4; ++mt) {
            float4 bv = *(const float4*)&g_b[m0 + wm + mt * 16 + quad * 4];
#pragma unroll
            for (int nt = 0; nt < 4; ++nt) {
                int col = wn + nt * 16 + lq;
                int mr = wm + mt * 16 + quad * 4;
                Cs[(mr + 0) * 136 + col] = (half_t)(acc[mt][nt][0] + bv.x);
                Cs[(mr + 1) * 136 + col] = (half_t)(acc[mt][nt][1] + bv.y);
                Cs[(mr + 2) * 136 + col] = (half_t)(acc[mt][nt][2] + bv.z);
                Cs[(mr + 3) * 136 + col] = (half_t)(acc[mt][nt][3] + bv.w);
            }
        }
        __syncthreads();
#pragma unroll
        for (int i = 0; i < 16; ++i) {
            int m = (tid >> 5) + 8 * i;
            int pw = tid & 31;
            float v0 = (float)Cs[m * 136 + 2 * pw];
            float v1 = (float)Cs[m * 136 + 2 * pw + 1];
            float v2 = (float)Cs[m * 136 + 64 + 2 * pw];
            float v3 = (float)Cs[m * 136 + 65 + 2 * pw];
            g16[((size_t)n * C2 + m0 + m) * PP + (p0 >> 7) * 32 + pw] =
                (half_t)fmaxf(fmaxf(v0, v1), fmaxf(v2, v3));
        }
    }
}

// ---------------------------------------------------------------------------
// Fused flash-attention + output conv. Block = (n, 64 q), 4 waves.
// Round-0 core (proven 80 us; VGPR 124, LDS 36.9 KB, 2 blocks/CU) with
// XCD swizzle: 1D grid 512, n = bid & 7 -> each XCD keeps ONE n's phi+g
// (640 KB) L2-resident across all 64 q-blocks; PV's g-loads (MFMA critical
// path) hit L2 (~200cy) instead of HBM (~900cy).
// ---------------------------------------------------------------------------
__global__ __launch_bounds__(256, 2) void attn_fused_k(
    const half_t* __restrict__ theta16,   // [n][4096][64]
    const half_t* __restrict__ phi16,     // [n][1024][64]
    const half_t* __restrict__ g16,       // [n][256][1024]
    const half_t* __restrict__ W16o,      // [512][256] fp16
    const float* __restrict__ out_b,      // [512]
    const float* __restrict__ x,          // [n][512][4096] fp32
    const float* __restrict__ gam,
    float* __restrict__ outF)             // [n][512][4096] fp32
{
    __shared__ half_t P[64][264];          // 33792 B (scores, then O^T)
    __shared__ float redM[4][64];
    __shared__ float redS[4][64];
    __shared__ float Ms[64], alpha_s[64], l_s[64], inv_s[64];

    const int tid  = threadIdx.x;
    const int wave = tid >> 6;
    const int lane = tid & 63;
    const int quad = lane >> 4;
    const int lq   = lane & 15;
    const int n  = blockIdx.x & 7;          // XCD-aware: one n per XCD
    const int q0 = (blockIdx.x >> 3) * 64;
    const int cb = wave * 64;

    const half_t* thN  = theta16 + ((size_t)n * HW + q0) * 64;
    const half_t* phiN = phi16 + (size_t)n * PP * 64;
    const half_t* gN   = g16 + (size_t)n * C2 * PP;

    if (tid < 64) { Ms[tid] = -1e30f; l_s[tid] = 0.f; }

    f32x4 acc[4][4];   // [ct][qt] : rows c, cols q
#pragma unroll
    for (int ct = 0; ct < 4; ++ct)
#pragma unroll
        for (int qt = 0; qt < 4; ++qt)
            acc[ct][qt] = (f32x4){0.f, 0.f, 0.f, 0.f};

    for (int chunk = 0; chunk < 4; ++chunk) {
        const int pch = chunk * 256;

        // --- E phase: wave covers 64 p of chunk ---
        half8 tb[4][2];
#pragma unroll
        for (int qt = 0; qt < 4; ++qt)
#pragma unroll
            for (int kb = 0; kb < 2; ++kb)
                tb[qt][kb] = *(const half8*)&thN[(size_t)(qt * 16 + lq) * 64 + kb * 32 + quad * 8];

        float mreg[4] = {-1e30f, -1e30f, -1e30f, -1e30f};
#pragma unroll
        for (int pt = 0; pt < 4; ++pt) {
            int pl = wave * 64 + pt * 16;
            const half_t* pr = &phiN[(size_t)(pch + pl + lq) * 64];
            half8 a0 = *(const half8*)&pr[quad * 8];
            half8 a1 = *(const half8*)&pr[32 + quad * 8];
#pragma unroll
            for (int qt = 0; qt < 4; ++qt) {
                f32x4 c = {0.f, 0.f, 0.f, 0.f};
                c = __builtin_amdgcn_mfma_f32_16x16x32_f16(a0, tb[qt][0], c, 0, 0, 0);
                c = __builtin_amdgcn_mfma_f32_16x16x32_f16(a1, tb[qt][1], c, 0, 0, 0);
                mreg[qt] = fmaxf(mreg[qt], fmaxf(fmaxf(c[0], c[1]), fmaxf(c[2], c[3])));
                half2t h0; h0[0] = (half_t)c[0]; h0[1] = (half_t)c[1];
                half2t h1; h1[0] = (half_t)c[2]; h1[1] = (half_t)c[3];
                *(half2t*)&P[qt * 16 + lq][pl + quad * 4]     = h0;
                *(half2t*)&P[qt * 16 + lq][pl + quad * 4 + 2] = h1;
            }
        }
#pragma unroll
        for (int qt = 0; qt < 4; ++qt) {
            float m = mreg[qt];
            m = fmaxf(m, __shfl_xor(m, 16));
            m = fmaxf(m, __shfl_xor(m, 32));
            mreg[qt] = m;
        }
        if (quad == 0) {
#pragma unroll
            for (int qt = 0; qt < 4; ++qt) redM[wave][qt * 16 + lq] = mreg[qt];
        }
        __syncthreads();                                   // B1

        if (tid < 64) {
            float cm = fmaxf(fmaxf(redM[0][tid], redM[1][tid]),
                             fmaxf(redM[2][tid], redM[3][tid]));
            float Mo = Ms[tid];
            float Mn = fmaxf(Mo, cm);
            alpha_s[tid] = __expf(Mo - Mn);
            Ms[tid] = Mn;
        }
        __syncthreads();                                   // B2

        // rescale O accumulators
        {
            float al[4];
#pragma unroll
            for (int qt = 0; qt < 4; ++qt) al[qt] = alpha_s[qt * 16 + lq];
#pragma unroll
            for (int ct = 0; ct < 4; ++ct)
#pragma unroll
                for (int qt = 0; qt < 4; ++qt)
#pragma unroll
                    for (int r = 0; r < 4; ++r) acc[ct][qt][r] *= al[qt];
        }

        // exp pass: thread = (q = tid&63, seg = wave)
        {
            int q = tid & 63, seg = tid >> 6;
            float M = Ms[q];
            float s = 0.f;
#pragma unroll
            for (int j = 0; j < 8; ++j) {
                half8 v = *(const half8*)&P[q][seg * 64 + j * 8];
                half8 o;
#pragma unroll
                for (int e = 0; e < 8; ++e) {
                    float f = __expf((float)v[e] - M);
                    s += f;
                    o[e] = (half_t)f;
                }
                *(half8*)&P[q][seg * 64 + j * 8] = o;
            }
            redS[seg][q] = s;
        }
        __syncthreads();                                   // B3

        if (tid < 64)
            l_s[tid] = l_s[tid] * alpha_s[tid]
                     + redS[0][tid] + redS[1][tid] + redS[2][tid] + redS[3][tid];

        // --- PV: wave covers c in [cb, cb+64); k over this chunk ---
#pragma unroll
        for (int kb = 0; kb < 8; ++kb) {
            half8 b[4];
#pragma unroll
            for (int qt = 0; qt < 4; ++qt)
                b[qt] = *(const half8*)&P[qt * 16 + lq][kb * 32 + quad * 8];
#pragma unroll
            for (int ct = 0; ct < 4; ++ct) {
                half8 a = *(const half8*)&gN[(size_t)(cb + ct * 16 + lq) * PP + pch + kb * 32 + quad * 8];
#pragma unroll
                for (int qt = 0; qt < 4; ++qt)
                    acc[ct][qt] = __builtin_amdgcn_mfma_f32_16x16x32_f16(a, b[qt], acc[ct][qt], 0, 0, 0);
            }
        }
        __syncthreads();                                   // B4
    }

    if (tid < 64) inv_s[tid] = 1.0f / l_s[tid];
    __syncthreads();

    // stage O^T fp16 into P as [q][c]
    {
        float iv[4];
#pragma unroll
        for (int qt = 0; qt < 4; ++qt) iv[qt] = inv_s[qt * 16 + lq];
#pragma unroll
        for (int ct = 0; ct < 4; ++ct) {
#pragma unroll
            for (int qt = 0; qt < 4; ++qt) {
                half2t h0, h1;
                h0[0] = (half_t)(acc[ct][qt][0] * iv[qt]);
                h0[1] = (half_t)(acc[ct][qt][1] * iv[qt]);
                h1[0] = (half_t)(acc[ct][qt][2] * iv[qt]);
                h1[1] = (half_t)(acc[ct][qt][3] * iv[qt]);
                *(half2t*)&P[qt * 16 + lq][cb + ct * 16 + quad * 4]     = h0;
                *(half2t*)&P[qt * 16 + lq][cb + ct * 16 + quad * 4 + 2] = h1;
            }
        }
    }
    __syncthreads();

    // out-GEMM: [512 m][64 q] over k=256, 2 m-passes
    const float g0 = gam[0];
#pragma unroll
    for (int pass = 0; pass < 2; ++pass) {
        const int mb = pass * 256 + wave * 64;
        f32x4 acc2[4][4];
#pragma unroll
        for (int mt = 0; mt < 4; ++mt)
#pragma unroll
            for (int qt = 0; qt < 4; ++qt)
                acc2[mt][qt] = (f32x4){0.f, 0.f, 0.f, 0.f};

#pragma unroll
        for (int kb = 0; kb < 8; ++kb) {
            half8 b[4];
#pragma unroll
            for (int qt = 0; qt < 4; ++qt)
                b[qt] = *(const half8*)&P[qt * 16 + lq][kb * 32 + quad * 8];
#pragma unroll
            for (int mt = 0; mt < 4; ++mt) {
                half8 a = *(const half8*)&W16o[(size_t)(mb + mt * 16 + lq) * 256 + kb * 32 + quad * 8];
#pragma unroll
                for (int qt = 0; qt < 4; ++qt)
                    acc2[mt][qt] = __builtin_amdgcn_mfma_f32_16x16x32_f16(a, b[qt], acc2[mt][qt], 0, 0, 0);
            }
        }

#pragma unroll
        for (int mt = 0; mt < 4; ++mt) {
            float4 bv = *(const float4*)&out_b[mb + mt * 16 + quad * 4];
#pragma unroll
            for (int qt = 0; qt < 4; ++qt) {
                int qg = q0 + qt * 16 + lq;
                int m = mb + mt * 16 + quad * 4;
                size_t off = ((size_t)(n * 512 + m)) * HW + qg;
                outF[off]          = g0 * (acc2[mt][qt][0] + bv.x) + x[off];
                outF[off + HW]     = g0 * (acc2[mt][qt][1] + bv.y) + x[off + HW];
                outF[off + 2*HW]   = g0 * (acc2[mt][qt][2] + bv.z) + x[off + 2*HW];
                outF[off + 3*HW]   = g0 * (acc2[mt][qt][3] + bv.w) + x[off + 3*HW];
            }
        }
    }
}

// ---------------------------------------------------------------------------
extern "C" void kernel_launch(void* const* d_in, const int* in_sizes, int n_in,
                              void* d_out, int out_size, void* d_ws, size_t ws_size,
                              hipStream_t stream)
{
    const float* x       = (const float*)d_in[0];
    const float* theta_w = (const float*)d_in[1];
    const float* theta_b = (const float*)d_in[2];
    const float* phi_w   = (const float*)d_in[3];
    const float* phi_b   = (const float*)d_in[4];
    const float* g_w     = (const float*)d_in[5];
    const float* g_b     = (const float*)d_in[6];
    const float* out_w   = (const float*)d_in[7];
    const float* out_b   = (const float*)d_in[8];
    const float* gamma   = (const float*)d_in[9];
    float* out = (float*)d_out;

    char* wsb = (char*)d_ws;
    half_t* x16t    = (half_t*)wsb;                    // 33,554,432 B
    half_t* W16     = (half_t*)(wsb + 33554432);       // 655,360 B
    half_t* theta16 = (half_t*)(wsb + 34209792);       // 4,194,304 B
    half_t* phi16   = (half_t*)(wsb + 38404096);       // 1,048,576 B
    half_t* g16     = (half_t*)(wsb + 39452672);       // 4,194,304 B

    // 1) weights -> fp16
    cast_w_k<<<160, 256, 0, stream>>>(theta_w, phi_w, g_w, out_w, W16);
    // 2) x -> x16t [n][p][c] fp16
    cast_xt_k<<<dim3(512, NB), 256, 0, stream>>>(x, x16t);
    // 3) all projections, 1D grid with n = bid&7 (XCD-local x16t reuse)
    proj_k<<<768, 256, 0, stream>>>(
        W16, theta_b, phi_b, g_b, x16t, theta16, phi16, g16);
    // 4) fused flash attention + output conv, 1D grid with n = bid&7
    attn_fused_k<<<512, 256, 0, stream>>>(
        theta16, phi16, g16, W16 + 196608, out_b, x, gamma, out);
}

// Round 9
// 209.825 us; speedup vs baseline: 1.0396x; 1.0140x over previous
//
#include <hip/hip_runtime.h>
#include <hip/hip_bf16.h>
#include <cmath>
#include <cstdint>

#define NB 8
#define HW 4096
#define PP 1024
#define C2 256

typedef _Float16 half_t;
typedef _Float16 half8 __attribute__((ext_vector_type(8)));
typedef _Float16 half4 __attribute__((ext_vector_type(4)));
typedef _Float16 half2t __attribute__((ext_vector_type(2)));
typedef float f32x4 __attribute__((ext_vector_type(4)));

// ---------------------------------------------------------------------------
// Merged prep kernel.
//  blocks [0,160):  cast weights fp32->fp16 into W16
//  blocks >=160:    cast+transpose x [n][512 c][4096 p] fp32 ->
//                   x16t [n][4096 p][512 c] fp16.
// Transpose LDS: T[64 p][72] with 16B-chunk DIAGONAL SKEW
//   chunk(c,row) = ((c>>3) + ((row>>2)&7)) & 7.
// Writes (scalar u16, lanes vary p4 by 4): without skew, bank base
// 4*p4 mod 32 hits only {0,16} -> 16-way conflict; skew spreads to 8 bases
// -> ~4-way. Reads (half8) stay 16B-aligned and bank-balanced (8 row-bases
// x 8 chunk-perms cover 32 banks at the 8-access/bank minimum).
// ---------------------------------------------------------------------------
__global__ __launch_bounds__(256) void prep_k(
    const float* __restrict__ tw, const float* __restrict__ pw,
    const float* __restrict__ gw, const float* __restrict__ ow,
    half_t* __restrict__ W16,
    const float* __restrict__ x, half_t* __restrict__ x16t)
{
    const int tid = threadIdx.x;
    const int bx = blockIdx.x;

    if (bx < 160) {
        int gid = bx * 256 + tid;
        size_t i0 = (size_t)gid * 8;
        const float* src; size_t off;
        if (i0 < 32768)       { src = tw; off = i0; }
        else if (i0 < 65536)  { src = pw; off = i0 - 32768; }
        else if (i0 < 196608) { src = gw; off = i0 - 65536; }
        else                  { src = ow; off = i0 - 196608; }
        float4 a = *(const float4*)&src[off];
        float4 b = *(const float4*)&src[off + 4];
        half8 h;
        h[0] = (half_t)a.x; h[1] = (half_t)a.y; h[2] = (half_t)a.z; h[3] = (half_t)a.w;
        h[4] = (half_t)b.x; h[5] = (half_t)b.y; h[6] = (half_t)b.z; h[7] = (half_t)b.w;
        *(half8*)&W16[i0] = h;
        return;
    }

    __shared__ half_t T[64][72];
    const int b = bx - 160;
    const int n   = b >> 9;
    const int bxx = b & 511;
    const int c0 = (bxx & 7) * 64;
    const int p0 = (bxx >> 3) * 64;

#pragma unroll
    for (int it = 0; it < 4; ++it) {
        int c = (tid >> 4) + 16 * it;        // column (channel) 0..63
        int p4 = (tid & 15) * 4;             // row base (pixel)
        float4 v = *(const float4*)&x[((size_t)n * 512 + c0 + c) * HW + p0 + p4];
        float vv[4] = {v.x, v.y, v.z, v.w};
#pragma unroll
        for (int k = 0; k < 4; ++k) {
            int row = p4 + k;
            int chunk = (((c >> 3) + ((row >> 2) & 7)) & 7);
            T[row][chunk * 8 + (c & 7)] = (half_t)vv[k];
        }
    }
    __syncthreads();
#pragma unroll
    for (int it = 0; it < 2; ++it) {
        int p = (tid >> 3) + 32 * it;
        int ch = (tid & 7) * 8;
        int chunk = (((ch >> 3) + ((p >> 2) & 7)) & 7);
        half8 o = *(const half8*)&T[p][chunk * 8];
        *(half8*)&x16t[((size_t)n * HW + p0 + p) * 512 + c0 + ch] = o;
    }
}

// ---------------------------------------------------------------------------
// Fused projection GEMM, 128x128 tile, BK=64, 4 waves (r8 version, proven).
// global_load_lds staging, linear LDS + XOR swizzle both sides (rule #21).
// 1D grid, n = bid & 7: XCD-local x16t reuse (FETCH -18MB, r8).
// ---------------------------------------------------------------------------
#define SWZ(row, chunk) (((row) << 6) + ((((chunk) ^ ((row) & 7))) << 3))

__global__ __launch_bounds__(256, 2) void proj_k(
    const half_t* __restrict__ W16, const float* __restrict__ theta_b,
    const float* __restrict__ phi_b, const float* __restrict__ g_b,
    const half_t* __restrict__ x16t, half_t* __restrict__ theta16,
    half_t* __restrict__ phi16, half_t* __restrict__ g16)
{
    __shared__ __align__(16) char smem[36864];
    half_t* As = (half_t*)smem;              // [128][64] linear, swizzled
    half_t* Bs = (half_t*)(smem + 16384);    // [128][64] linear, swizzled

    const int tid = threadIdx.x;
    const int wave = tid >> 6, lane = tid & 63;
    const int quad = lane >> 4, lq = lane & 15;
    const int wn = (wave & 1) * 64, wm = (wave >> 1) * 64;

    const int bid  = blockIdx.x;
    const int n    = bid & 7;
    const int rest = bid >> 3;            // 0..95
    const int p0   = (rest & 31) * 128;
    const int ysel = rest >> 5;           // 0..2

    const half_t* A16 = (ysel == 0) ? W16
                        : (W16 + 65536 + (size_t)(ysel - 1) * 128 * 512);

    const int sr  = lane >> 3;          // row-within-8-group
    const int scl = lane & 7;           // LDS chunk this lane's slot holds
    const int scg = scl ^ sr;           // global chunk to fetch (involution)

    f32x4 acc[4][4];
#pragma unroll
    for (int mt = 0; mt < 4; ++mt)
#pragma unroll
        for (int nt = 0; nt < 4; ++nt)
            acc[mt][nt] = (f32x4){0.f, 0.f, 0.f, 0.f};

    for (int c0 = 0; c0 < 512; c0 += 64) {
#pragma unroll
        for (int i = 0; i < 4; ++i) {
            int rb = (wave << 5) + (i << 3);        // wave-uniform row base
            int r = rb + sr;
            __builtin_amdgcn_global_load_lds(
                (const __attribute__((address_space(1))) uint32_t*)
                    &A16[(size_t)r * 512 + c0 + scg * 8],
                (__attribute__((address_space(3))) uint32_t*)&As[rb * 64],
                16, 0, 0);
        }
#pragma unroll
        for (int i = 0; i < 4; ++i) {
            int rb = (wave << 5) + (i << 3);
            int r = rb + sr;
            __builtin_amdgcn_global_load_lds(
                (const __attribute__((address_space(1))) uint32_t*)
                    &x16t[((size_t)n * HW + p0 + r) * 512 + c0 + scg * 8],
                (__attribute__((address_space(3))) uint32_t*)&Bs[rb * 64],
                16, 0, 0);
        }
        __syncthreads();
#pragma unroll
        for (int ks = 0; ks < 2; ++ks) {
            half8 af[4], bf[4];
#pragma unroll
            for (int mt = 0; mt < 4; ++mt)
                af[mt] = *(const half8*)&As[SWZ(wm + mt * 16 + lq, ks * 4 + quad)];
#pragma unroll
            for (int nt = 0; nt < 4; ++nt)
                bf[nt] = *(const half8*)&Bs[SWZ(wn + nt * 16 + lq, ks * 4 + quad)];
#pragma unroll
            for (int mt = 0; mt < 4; ++mt)
#pragma unroll
                for (int nt = 0; nt < 4; ++nt)
                    acc[mt][nt] = __builtin_amdgcn_mfma_f32_16x16x32_f16(
                        af[mt], bf[nt], acc[mt][nt], 0, 0, 0);
        }
        __syncthreads();
    }

    if (ysel == 0) {
        half_t* Cs = (half_t*)smem;   // [64][136] phi C-tile
        if (wm == 0) {
#pragma unroll
            for (int mt = 0; mt < 4; ++mt) {
                float4 bv = *(const float4*)&theta_b[mt * 16 + quad * 4];
#pragma unroll
                for (int nt = 0; nt < 4; ++nt) {
                    int q = p0 + wn + nt * 16 + lq;
                    half4 h;
                    h[0] = (half_t)(acc[mt][nt][0] + bv.x);
                    h[1] = (half_t)(acc[mt][nt][1] + bv.y);
                    h[2] = (half_t)(acc[mt][nt][2] + bv.z);
                    h[3] = (half_t)(acc[mt][nt][3] + bv.w);
                    *(half4*)&theta16[((size_t)n * HW + q) * 64 + mt * 16 + quad * 4] = h;
                }
            }
        } else {
#pragma unroll
            for (int mt = 0; mt < 4; ++mt) {
                float4 bv = *(const float4*)&phi_b[mt * 16 + quad * 4];
#pragma unroll
                for (int nt = 0; nt < 4; ++nt) {
                    int col = wn + nt * 16 + lq;
                    int mr = mt * 16 + quad * 4;
                    Cs[(mr + 0) * 136 + col] = (half_t)(acc[mt][nt][0] + bv.x);
                    Cs[(mr + 1) * 136 + col] = (half_t)(acc[mt][nt][1] + bv.y);
                    Cs[(mr + 2) * 136 + col] = (half_t)(acc[mt][nt][2] + bv.z);
                    Cs[(mr + 3) * 136 + col] = (half_t)(acc[mt][nt][3] + bv.w);
                }
            }
        }
        __syncthreads();
        {
            int pw = tid >> 3;
            int kc = (tid & 7) * 8;
            half8 o;
#pragma unroll
            for (int jj = 0; jj < 8; ++jj) {
                int k = kc + jj;
                float v0 = (float)Cs[k * 136 + 2 * pw];
                float v1 = (float)Cs[k * 136 + 2 * pw + 1];
                float v2 = (float)Cs[k * 136 + 64 + 2 * pw];
                float v3 = (float)Cs[k * 136 + 65 + 2 * pw];
                o[jj] = (half_t)fmaxf(fmaxf(v0, v1), fmaxf(v2, v3));
            }
            *(half8*)&phi16[((size_t)n * PP + (p0 >> 7) * 32 + pw) * 64 + kc] = o;
        }
    } else {
        const int m0 = (ysel - 1) * 128;
        half_t* Cs = (half_t*)smem;   // [128][136]
#pragma unroll
        for (int mt = 0; mt < 4; ++mt) {
            float4 bv = *(const float4*)&g_b[m0 + wm + mt * 16 + quad * 4];
#pragma unroll
            for (int nt = 0; nt < 4; ++nt) {
                int col = wn + nt * 16 + lq;
                int mr = wm + mt * 16 + quad * 4;
                Cs[(mr + 0) * 136 + col] = (half_t)(acc[mt][nt][0] + bv.x);
                Cs[(mr + 1) * 136 + col] = (half_t)(acc[mt][nt][1] + bv.y);
                Cs[(mr + 2) * 136 + col] = (half_t)(acc[mt][nt][2] + bv.z);
                Cs[(mr + 3) * 136 + col] = (half_t)(acc[mt][nt][3] + bv.w);
            }
        }
        __syncthreads();
#pragma unroll
        for (int i = 0; i < 16; ++i) {
            int m = (tid >> 5) + 8 * i;
            int pw = tid & 31;
            float v0 = (float)Cs[m * 136 + 2 * pw];
            float v1 = (float)Cs[m * 136 + 2 * pw + 1];
            float v2 = (float)Cs[m * 136 + 64 + 2 * pw];
            float v3 = (float)Cs[m * 136 + 65 + 2 * pw];
            g16[((size_t)n * C2 + m0 + m) * PP + (p0 >> 7) * 32 + pw] =
                (half_t)fmaxf(fmaxf(v0, v1), fmaxf(v2, v3));
        }
    }
}

// ---------------------------------------------------------------------------
// Fused flash-attention + output conv (r8 version, proven 80us floor).
// Round-0 core + XCD swizzle (n = bid&7; FETCH 57->39MB, time-neutral).
// ---------------------------------------------------------------------------
__global__ __launch_bounds__(256, 2) void attn_fused_k(
    const half_t* __restrict__ theta16,   // [n][4096][64]
    const half_t* __restrict__ phi16,     // [n][1024][64]
    const half_t* __restrict__ g16,       // [n][256][1024]
    const half_t* __restrict__ W16o,      // [512][256] fp16
    const float* __restrict__ out_b,      // [512]
    const float* __restrict__ x,          // [n][512][4096] fp32
    const float* __restrict__ gam,
    float* __restrict__ outF)             // [n][512][4096] fp32
{
    __shared__ half_t P[64][264];          // 33792 B (scores, then O^T)
    __shared__ float redM[4][64];
    __shared__ float redS[4][64];
    __shared__ float Ms[64], alpha_s[64], l_s[64], inv_s[64];

    const int tid  = threadIdx.x;
    const int wave = tid >> 6;
    const int lane = tid & 63;
    const int quad = lane >> 4;
    const int lq   = lane & 15;
    const int n  = blockIdx.x & 7;          // XCD-aware: one n per XCD
    const int q0 = (blockIdx.x >> 3) * 64;
    const int cb = wave * 64;

    const half_t* thN  = theta16 + ((size_t)n * HW + q0) * 64;
    const half_t* phiN = phi16 + (size_t)n * PP * 64;
    const half_t* gN   = g16 + (size_t)n * C2 * PP;

    if (tid < 64) { Ms[tid] = -1e30f; l_s[tid] = 0.f; }

    f32x4 acc[4][4];   // [ct][qt] : rows c, cols q
#pragma unroll
    for (int ct = 0; ct < 4; ++ct)
#pragma unroll
        for (int qt = 0; qt < 4; ++qt)
            acc[ct][qt] = (f32x4){0.f, 0.f, 0.f, 0.f};

    for (int chunk = 0; chunk < 4; ++chunk) {
        const int pch = chunk * 256;

        // --- E phase: wave covers 64 p of chunk ---
        half8 tb[4][2];
#pragma unroll
        for (int qt = 0; qt < 4; ++qt)
#pragma unroll
            for (int kb = 0; kb < 2; ++kb)
                tb[qt][kb] = *(const half8*)&thN[(size_t)(qt * 16 + lq) * 64 + kb * 32 + quad * 8];

        float mreg[4] = {-1e30f, -1e30f, -1e30f, -1e30f};
#pragma unroll
        for (int pt = 0; pt < 4; ++pt) {
            int pl = wave * 64 + pt * 16;
            const half_t* pr = &phiN[(size_t)(pch + pl + lq) * 64];
            half8 a0 = *(const half8*)&pr[quad * 8];
            half8 a1 = *(const half8*)&pr[32 + quad * 8];
#pragma unroll
            for (int qt = 0; qt < 4; ++qt) {
                f32x4 c = {0.f, 0.f, 0.f, 0.f};
                c = __builtin_amdgcn_mfma_f32_16x16x32_f16(a0, tb[qt][0], c, 0, 0, 0);
                c = __builtin_amdgcn_mfma_f32_16x16x32_f16(a1, tb[qt][1], c, 0, 0, 0);
                mreg[qt] = fmaxf(mreg[qt], fmaxf(fmaxf(c[0], c[1]), fmaxf(c[2], c[3])));
                half2t h0; h0[0] = (half_t)c[0]; h0[1] = (half_t)c[1];
                half2t h1; h1[0] = (half_t)c[2]; h1[1] = (half_t)c[3];
                *(half2t*)&P[qt * 16 + lq][pl + quad * 4]     = h0;
                *(half2t*)&P[qt * 16 + lq][pl + quad * 4 + 2] = h1;
            }
        }
#pragma unroll
        for (int qt = 0; qt < 4; ++qt) {
            float m = mreg[qt];
            m = fmaxf(m, __shfl_xor(m, 16));
            m = fmaxf(m, __shfl_xor(m, 32));
            mreg[qt] = m;
        }
        if (quad == 0) {
#pragma unroll
            for (int qt = 0; qt < 4; ++qt) redM[wave][qt * 16 + lq] = mreg[qt];
        }
        __syncthreads();                                   // B1

        if (tid < 64) {
            float cm = fmaxf(fmaxf(redM[0][tid], redM[1][tid]),
                             fmaxf(redM[2][tid], redM[3][tid]));
            float Mo = Ms[tid];
            float Mn = fmaxf(Mo, cm);
            alpha_s[tid] = __expf(Mo - Mn);
            Ms[tid] = Mn;
        }
        __syncthreads();                                   // B2

        // rescale O accumulators
        {
            float al[4];
#pragma unroll
            for (int qt = 0; qt < 4; ++qt) al[qt] = alpha_s[qt * 16 + lq];
#pragma unroll
            for (int ct = 0; ct < 4; ++ct)
#pragma unroll
                for (int qt = 0; qt < 4; ++qt)
#pragma unroll
                    for (int r = 0; r < 4; ++r) acc[ct][qt][r] *= al[qt];
        }

        // exp pass: thread = (q = tid&63, seg = wave)
        {
            int q = tid & 63, seg = tid >> 6;
            float M = Ms[q];
            float s = 0.f;
#pragma unroll
            for (int j = 0; j < 8; ++j) {
                half8 v = *(const half8*)&P[q][seg * 64 + j * 8];
                half8 o;
#pragma unroll
                for (int e = 0; e < 8; ++e) {
                    float f = __expf((float)v[e] - M);
                    s += f;
                    o[e] = (half_t)f;
                }
                *(half8*)&P[q][seg * 64 + j * 8] = o;
            }
            redS[seg][q] = s;
        }
        __syncthreads();                                   // B3

        if (tid < 64)
            l_s[tid] = l_s[tid] * alpha_s[tid]
                     + redS[0][tid] + redS[1][tid] + redS[2][tid] + redS[3][tid];

        // --- PV: wave covers c in [cb, cb+64); k over this chunk ---
#pragma unroll
        for (int kb = 0; kb < 8; ++kb) {
            half8 b[4];
#pragma unroll
            for (int qt = 0; qt < 4; ++qt)
                b[qt] = *(const half8*)&P[qt * 16 + lq][kb * 32 + quad * 8];
#pragma unroll
            for (int ct = 0; ct < 4; ++ct) {
                half8 a = *(const half8*)&gN[(size_t)(cb + ct * 16 + lq) * PP + pch + kb * 32 + quad * 8];
#pragma unroll
                for (int qt = 0; qt < 4; ++qt)
                    acc[ct][qt] = __builtin_amdgcn_mfma_f32_16x16x32_f16(a, b[qt], acc[ct][qt], 0, 0, 0);
            }
        }
        __syncthreads();                                   // B4
    }

    if (tid < 64) inv_s[tid] = 1.0f / l_s[tid];
    __syncthreads();

    // stage O^T fp16 into P as [q][c]
    {
        float iv[4];
#pragma unroll
        for (int qt = 0; qt < 4; ++qt) iv[qt] = inv_s[qt * 16 + lq];
#pragma unroll
        for (int ct = 0; ct < 4; ++ct) {
#pragma unroll
            for (int qt = 0; qt < 4; ++qt) {
                half2t h0, h1;
                h0[0] = (half_t)(acc[ct][qt][0] * iv[qt]);
                h0[1] = (half_t)(acc[ct][qt][1] * iv[qt]);
                h1[0] = (half_t)(acc[ct][qt][2] * iv[qt]);
                h1[1] = (half_t)(acc[ct][qt][3] * iv[qt]);
                *(half2t*)&P[qt * 16 + lq][cb + ct * 16 + quad * 4]     = h0;
                *(half2t*)&P[qt * 16 + lq][cb + ct * 16 + quad * 4 + 2] = h1;
            }
        }
    }
    __syncthreads();

    // out-GEMM: [512 m][64 q] over k=256, 2 m-passes
    const float g0 = gam[0];
#pragma unroll
    for (int pass = 0; pass < 2; ++pass) {
        const int mb = pass * 256 + wave * 64;
        f32x4 acc2[4][4];
#pragma unroll
        for (int mt = 0; mt < 4; ++mt)
#pragma unroll
            for (int qt = 0; qt < 4; ++qt)
                acc2[mt][qt] = (f32x4){0.f, 0.f, 0.f, 0.f};

#pragma unroll
        for (int kb = 0; kb < 8; ++kb) {
            half8 b[4];
#pragma unroll
            for (int qt = 0; qt < 4; ++qt)
                b[qt] = *(const half8*)&P[qt * 16 + lq][kb * 32 + quad * 8];
#pragma unroll
            for (int mt = 0; mt < 4; ++mt) {
                half8 a = *(const half8*)&W16o[(size_t)(mb + mt * 16 + lq) * 256 + kb * 32 + quad * 8];
#pragma unroll
                for (int qt = 0; qt < 4; ++qt)
                    acc2[mt][qt] = __builtin_amdgcn_mfma_f32_16x16x32_f16(a, b[qt], acc2[mt][qt], 0, 0, 0);
            }
        }

#pragma unroll
        for (int mt = 0; mt < 4; ++mt) {
            float4 bv = *(const float4*)&out_b[mb + mt * 16 + quad * 4];
#pragma unroll
            for (int qt = 0; qt < 4; ++qt) {
                int qg = q0 + qt * 16 + lq;
                int m = mb + mt * 16 + quad * 4;
                size_t off = ((size_t)(n * 512 + m)) * HW + qg;
                outF[off]          = g0 * (acc2[mt][qt][0] + bv.x) + x[off];
                outF[off + HW]     = g0 * (acc2[mt][qt][1] + bv.y) + x[off + HW];
                outF[off + 2*HW]   = g0 * (acc2[mt][qt][2] + bv.z) + x[off + 2*HW];
                outF[off + 3*HW]   = g0 * (acc2[mt][qt][3] + bv.w) + x[off + 3*HW];
            }
        }
    }
}

// ---------------------------------------------------------------------------
extern "C" void kernel_launch(void* const* d_in, const int* in_sizes, int n_in,
                              void* d_out, int out_size, void* d_ws, size_t ws_size,
                              hipStream_t stream)
{
    const float* x       = (const float*)d_in[0];
    const float* theta_w = (const float*)d_in[1];
    const float* theta_b = (const float*)d_in[2];
    const float* phi_w   = (const float*)d_in[3];
    const float* phi_b   = (const float*)d_in[4];
    const float* g_w     = (const float*)d_in[5];
    const float* g_b     = (const float*)d_in[6];
    const float* out_w   = (const float*)d_in[7];
    const float* out_b   = (const float*)d_in[8];
    const float* gamma   = (const float*)d_in[9];
    float* out = (float*)d_out;

    char* wsb = (char*)d_ws;
    half_t* x16t    = (half_t*)wsb;                    // 33,554,432 B
    half_t* W16     = (half_t*)(wsb + 33554432);       // 655,360 B
    half_t* theta16 = (half_t*)(wsb + 34209792);       // 4,194,304 B
    half_t* phi16   = (half_t*)(wsb + 38404096);       // 1,048,576 B
    half_t* g16     = (half_t*)(wsb + 39452672);       // 4,194,304 B

    // 1) weights -> fp16 AND x -> x16t (merged, one launch)
    prep_k<<<160 + 512 * NB, 256, 0, stream>>>(
        theta_w, phi_w, g_w, out_w, W16, x, x16t);
    // 2) all projections, 1D grid with n = bid&7 (XCD-local x16t reuse)
    proj_k<<<768, 256, 0, stream>>>(
        W16, theta_b, phi_b, g_b, x16t, theta16, phi16, g16);
    // 3) fused flash attention + output conv, 1D grid with n = bid&7
    attn_fused_k<<<512, 256, 0, stream>>>(
        theta16, phi16, g16, W16 + 196608, out_b, x, gamma, out);
}